// Round 11
// baseline (396.748 us; speedup 1.0000x reference)
//
#include <hip/hip_runtime.h>
#include <hip/hip_bf16.h>

// out[M,N] = x @ (W + 2*B@A)^T.  M=16384, N=2048, K=2048, R=64.
// R11: 8-phase skeleton + (a) 32x32x16 MFMA (2495 TF ceiling vs 2075, half the
// instr count) + (b) single barrier per phase (trailing barrier removed; VM4
// always precedes the remaining pre-MFMA barrier so gload->ds_read hazard holds).

typedef short short8 __attribute__((ext_vector_type(8)));
typedef float f32x16 __attribute__((ext_vector_type(16)));

__device__ __forceinline__ unsigned short f2bf(float f) {
  unsigned u = __float_as_uint(f);
  u += 0x7fff + ((u >> 16) & 1);
  return (unsigned short)(u >> 16);
}

// ---------------- pass 1: x fp32 -> bf16 ----------------
__global__ __launch_bounds__(256) void cvt_x_kernel(const float* __restrict__ x,
                                                    unsigned short* __restrict__ xb,
                                                    long long n) {
  long long idx = ((long long)blockIdx.x * 256 + threadIdx.x) * 8;
  long long stride = (long long)gridDim.x * 256 * 8;
  for (; idx < n; idx += stride) {
    float4 v0 = *(const float4*)(x + idx);
    float4 v1 = *(const float4*)(x + idx + 4);
    short8 o;
    o[0] = (short)f2bf(v0.x); o[1] = (short)f2bf(v0.y);
    o[2] = (short)f2bf(v0.z); o[3] = (short)f2bf(v0.w);
    o[4] = (short)f2bf(v1.x); o[5] = (short)f2bf(v1.y);
    o[6] = (short)f2bf(v1.z); o[7] = (short)f2bf(v1.w);
    *(short8*)(xb + idx) = o;
  }
}

// ---------------- pass 2: W_eff = bf16(W + scaling * B@A) ----------------
__global__ __launch_bounds__(256) void weff_kernel(const float* __restrict__ W,
                                                   const float* __restrict__ Alora,
                                                   const float* __restrict__ Blora,
                                                   unsigned short* __restrict__ Weff,
                                                   int N, int K, int R, float scaling) {
  __shared__ float Bs[16][64];
  int t = threadIdx.x;
  int ob = blockIdx.y * 16;
  int i = blockIdx.x * 256 + t;
  for (int j = t; j < 16 * 64; j += 256)
    Bs[j >> 6][j & 63] = Blora[(ob + (j >> 6)) * R + (j & 63)];
  __syncthreads();
  float acc[16];
#pragma unroll
  for (int o = 0; o < 16; ++o) acc[o] = 0.f;
#pragma unroll 8
  for (int r = 0; r < 64; ++r) {
    float av = Alora[r * K + i];
#pragma unroll
    for (int o = 0; o < 16; ++o) acc[o] = fmaf(Bs[o][r], av, acc[o]);
  }
#pragma unroll
  for (int o = 0; o < 16; ++o) {
    float w = W[(size_t)(ob + o) * K + i];
    Weff[(size_t)(ob + o) * K + i] = f2bf(w + scaling * acc[o]);
  }
}

// ---------------- pass 3: 8-phase 256^2 bf16 GEMM (32x32x16) ----------------
#define GLOAD_LDS16(g, l)                                                        \
  __builtin_amdgcn_global_load_lds((const __attribute__((address_space(1))) void*)(g), \
                                   (__attribute__((address_space(3))) void*)(l), 16, 0, 0)

// LDS slot (64KB): A-unit0 [256][32] @0, A-unit1 @16384, B-unit0 @32768,
// B-unit1 @49152.  Involution on unit-local byte addr: b ^= ((b>>7)&7)<<4.

__global__ __launch_bounds__(512, 2) void gemm32_kernel(const unsigned short* __restrict__ Xb,
                                                        const unsigned short* __restrict__ Wb,
                                                        float* __restrict__ out,
                                                        int M, int N, int K) {
  __shared__ __align__(16) char lds[131072];

  const int t = threadIdx.x;
  const int lane = t & 63;
  const int w = t >> 6;
  const int wr = w >> 2, wc = w & 3;   // 2M x 4N waves; wave tile 128x64

  // T1: bijective XCD swizzle (nwg=512, %8==0)
  const int nwg = gridDim.x, cpx = nwg >> 3;
  const int swz = (blockIdx.x & 7) * cpx + (blockIdx.x >> 3);
  const int nbn = N >> 8;
  const int bm = swz / nbn, bn = swz % nbn;

  f32x16 acc[4][2];
#pragma unroll
  for (int i = 0; i < 4; ++i)
#pragma unroll
    for (int j = 0; j < 2; ++j)
#pragma unroll
      for (int q = 0; q < 16; ++q) acc[i][j][q] = 0.f;

  // stage source (inverse-swizzled): LDS[d] <- element[sw(d)], d = t*16 (+8192)
  const int srow = (t >> 2) ^ ((t >> 5) & 1);
  const int scol = ((t & 3) ^ ((t >> 3) & 3)) * 8;  // elems
  const unsigned short* gA = Xb + (size_t)(bm * 256 + srow) * K + scol;
  const unsigned short* gB = Wb + (size_t)(bn * 256 + srow) * K + scol;

  // 32x32x16 frag addressing: A row = wr*128 + (lane&31), k = (lane>>5)*8 (+kq*16)
  // unit-local lin = row*64 + (lane>>5)*16 + (kq&1)*32 ; swz = lin ^ key<<4.
  const int lane31 = lane & 31, lhalf = lane >> 5;
  const int key = ((lane31 >> 1) & 7) << 4;
  const int linA = ((wr * 128 + lane31) * 64) + lhalf * 16;
  const int linB = ((wc * 64 + lane31) * 64) + lhalf * 16;
  const int aswz0 = linA ^ key,        aswz1 = (linA + 32) ^ key;
  const int bswz0 = linB ^ key,        bswz1 = (linB + 32) ^ key;

  short8 af0, af1, af2, af3, bf0, bf1;

#define STG_A(NS, KSU, KOFF)                                                    \
  GLOAD_LDS16(gA + (KOFF), lds + (NS) * 65536 + (KSU) * 16384 + t * 16);        \
  GLOAD_LDS16(gA + (size_t)128 * K + (KOFF),                                    \
              lds + (NS) * 65536 + (KSU) * 16384 + 8192 + t * 16);
#define STG_B(NS, KSU, KOFF)                                                    \
  GLOAD_LDS16(gB + (KOFF), lds + (NS) * 65536 + 32768 + (KSU) * 16384 + t * 16);\
  GLOAD_LDS16(gB + (size_t)128 * K + (KOFF),                                    \
              lds + (NS) * 65536 + 32768 + (KSU) * 16384 + 8192 + t * 16);

#define RD32(SLOT, KQ) {                                                        \
    const char* pa_ = lds + (SLOT) * 65536 + ((KQ) >> 1) * 16384                \
                      + (((KQ) & 1) ? aswz1 : aswz0);                           \
    af0 = *(const short8*)(pa_);                                                \
    af1 = *(const short8*)(pa_ + 2048);                                         \
    af2 = *(const short8*)(pa_ + 4096);                                         \
    af3 = *(const short8*)(pa_ + 6144);                                         \
    const char* pb_ = lds + (SLOT) * 65536 + 32768 + ((KQ) >> 1) * 16384        \
                      + (((KQ) & 1) ? bswz1 : bswz0);                           \
    bf0 = *(const short8*)(pb_);                                                \
    bf1 = *(const short8*)(pb_ + 2048); }

#define MM8                                                                     \
  acc[0][0] = __builtin_amdgcn_mfma_f32_32x32x16_bf16(af0, bf0, acc[0][0], 0, 0, 0); \
  acc[0][1] = __builtin_amdgcn_mfma_f32_32x32x16_bf16(af0, bf1, acc[0][1], 0, 0, 0); \
  acc[1][0] = __builtin_amdgcn_mfma_f32_32x32x16_bf16(af1, bf0, acc[1][0], 0, 0, 0); \
  acc[1][1] = __builtin_amdgcn_mfma_f32_32x32x16_bf16(af1, bf1, acc[1][1], 0, 0, 0); \
  acc[2][0] = __builtin_amdgcn_mfma_f32_32x32x16_bf16(af2, bf0, acc[2][0], 0, 0, 0); \
  acc[2][1] = __builtin_amdgcn_mfma_f32_32x32x16_bf16(af2, bf1, acc[2][1], 0, 0, 0); \
  acc[3][0] = __builtin_amdgcn_mfma_f32_32x32x16_bf16(af3, bf0, acc[3][0], 0, 0, 0); \
  acc[3][1] = __builtin_amdgcn_mfma_f32_32x32x16_bf16(af3, bf1, acc[3][1], 0, 0, 0);

#define VM4 asm volatile("s_waitcnt vmcnt(4)" ::: "memory");
#define VM0 asm volatile("s_waitcnt vmcnt(0)" ::: "memory");
#define NOP_

// One barrier per phase. VM always precedes the barrier; lgkmcnt(0)+sched_barrier
// after it (rule 18). No trailing barrier: next phase's ds_reads overlap MFMA drain.
#define PH32(SLOT, KQ, STG_STMT, WAIT_STMT)                                     \
  RD32(SLOT, KQ)                                                                \
  STG_STMT                                                                      \
  WAIT_STMT                                                                     \
  __builtin_amdgcn_s_barrier();                                                 \
  asm volatile("s_waitcnt lgkmcnt(0)" ::: "memory");                            \
  __builtin_amdgcn_sched_barrier(0);                                            \
  __builtin_amdgcn_s_setprio(1);                                                \
  MM8                                                                           \
  __builtin_amdgcn_s_setprio(0);

  // K-tile = 4 phases (kq 0..3). Stage next tile: A0, B0(+VM4), A1, B1(+VM4).
#define KTILE32(SLOT, NS, KNEXT)                                                \
  PH32(SLOT, 0, STG_A(NS, 0, KNEXT), NOP_)                                      \
  PH32(SLOT, 1, STG_B(NS, 0, KNEXT), VM4)                                       \
  PH32(SLOT, 2, STG_A(NS, 1, (KNEXT) + 32), NOP_)                               \
  PH32(SLOT, 3, STG_B(NS, 1, (KNEXT) + 32), VM4)

#define KTILE32_LAST(SLOT)                                                      \
  PH32(SLOT, 0, NOP_, NOP_)                                                     \
  PH32(SLOT, 1, NOP_, VM0)                                                      \
  PH32(SLOT, 2, NOP_, NOP_)                                                     \
  PH32(SLOT, 3, NOP_, NOP_)

  // prologue: stage K-tile 0 into slot 0; drain its unit0 pair.
  STG_A(0, 0, 0) STG_B(0, 0, 0) STG_A(0, 1, 32) STG_B(0, 1, 32)
  VM4
  __builtin_amdgcn_s_barrier();

  int kk = 64;
#pragma unroll 1
  for (int it = 0; it < 15; ++it) {   // computes tiles 0..29
    KTILE32(0, 1, kk) kk += 64;
    KTILE32(1, 0, kk) kk += 64;
  }
  KTILE32(0, 1, kk)   // tile 30, stages tile 31 (kk = 1984)
  KTILE32_LAST(1)     // tile 31

  // epilogue: 32x32 C/D layout: col = lane&31, row = (reg&3) + 8*(reg>>2) + 4*(lane>>5)
  const int orow0 = bm * 256 + wr * 128 + lhalf * 4;
  const int ocol0 = bn * 256 + wc * 64 + lane31;
#pragma unroll
  for (int i = 0; i < 4; ++i)
#pragma unroll
    for (int j = 0; j < 2; ++j) {
#pragma unroll
      for (int reg = 0; reg < 16; ++reg) {
        int row = orow0 + i * 32 + (reg & 3) + 8 * (reg >> 2);
        int col = ocol0 + j * 32;
        out[(size_t)row * N + col] = acc[i][j][reg];
      }
    }
}

extern "C" void kernel_launch(void* const* d_in, const int* in_sizes, int n_in,
                              void* d_out, int out_size, void* d_ws, size_t ws_size,
                              hipStream_t stream) {
  const float* x  = (const float*)d_in[0];
  const float* W  = (const float*)d_in[1];
  const float* Al = (const float*)d_in[2];
  const float* Bl = (const float*)d_in[3];
  float* out = (float*)d_out;

  const int K = 2048;
  const long long M = (long long)in_sizes[0] / K;  // 16384
  const int N = in_sizes[1] / K;                   // 2048
  const int R = in_sizes[2] / K;                   // 64

  unsigned short* xb   = (unsigned short*)d_ws;
  unsigned short* weff = xb + (size_t)M * K;       // ~76 MB of ws

  cvt_x_kernel<<<2048, 256, 0, stream>>>(x, xb, (long long)M * K);
  weff_kernel<<<dim3(K / 256, N / 16), 256, 0, stream>>>(W, Al, Bl, weff, N, K, R, 2.0f);
  gemm32_kernel<<<(N / 256) * (int)(M / 256), 512, 0, stream>>>(xb, weff, out, (int)M, N, K);
}